// Round 9
// 713.529 us; speedup vs baseline: 1.0516x; 1.0516x over previous
//
#include <hip/hip_runtime.h>
#include <hip/hip_bf16.h>

typedef unsigned short u16;
typedef __attribute__((ext_vector_type(8))) __bf16 bf16x8;
typedef __attribute__((ext_vector_type(4))) float f32x4;
typedef __attribute__((ext_vector_type(8))) unsigned short u16x8;

#define DEV __device__ __forceinline__

DEV float bf2f(u16 v){ union{unsigned u; float f;} c; c.u=((unsigned)v)<<16; return c.f; }
DEV u16 f2bf(float f){ union{float f; unsigned u;} c; c.f=f; unsigned r=c.u+0x7FFFu+((c.u>>16)&1u); return (u16)(r>>16); }
DEV f32x4 mfma16(bf16x8 a, bf16x8 b, f32x4 c){ return __builtin_amdgcn_mfma_f32_16x16x32_bf16(a,b,c,0,0,0); }

// dims: B=4, D=512, H=W=128, wsz=8, shift=4, heads=16, dh=32, L=64
// Inputs fp32 (measured R4), output fp32. Core pipeline bf16 MFMA.
// M = 65536 tokens (window-permuted order), window w holds rows [w*64, w*64+64)
// ws: A @0 (64MB, LN out -> attn O in-place) | QKVc @64MB (64MB: qkv chunks / out-proj C)
//     | params @128MB (~2.1MB bf16 copies)

// ---------------- K0: fused param convert fp32 -> bf16 ----------------
__global__ __launch_bounds__(256) void cvt_params_k(const float* __restrict__ wqkv, const float* __restrict__ wout,
                                                    const float* __restrict__ bout,
                                                    u16* __restrict__ wqkv_c, u16* __restrict__ wout_c,
                                                    u16* __restrict__ bout_c){
  int i = blockIdx.x*256 + threadIdx.x;
  if (i < 786432) wqkv_c[i] = f2bf(wqkv[i]);
  int j = i - 786432;
  if (j >= 0 && j < 262144) wout_c[j] = f2bf(wout[j]);
  int k = i - 1048576;
  if (k >= 0 && k < 512) bout_c[k] = f2bf(bout[k]);
}

// ---------------- K1: fused LayerNorm (stats + apply) + roll(-4,-4) + window permute ----------------
// 1024 blocks; block = 64 positions (fixed h_src, 64 consecutive w_src), all 512 d.
// Pass1: float4 loads (16 lanes span the 64-w row, 16 d-rows per block-instruction),
//        LDS reduction -> per-position mean/rstd.
// Pass2: re-read (L2-hot), apply LN into LDS tile [128 d][65 w], then write A with
//        wave-contiguous 256B row segments (full 64B lines -> no write amplification).
__global__ __launch_bounds__(256) void ln_fused_k(const float* __restrict__ x, const float* __restrict__ g,
                                                  const float* __restrict__ bta, u16* __restrict__ A){
  __shared__ float reds[16][64];
  __shared__ float redq[16][64];
  __shared__ float2 sstat[64];
  __shared__ float sg[512], sb2[512];
  __shared__ u16 tile[128*65];

  const int blk = blockIdx.x;
  const int b = blk >> 8, rem = blk & 255;
  const int h_src = rem >> 1, w0 = (rem & 1) << 6;
  const int tid = threadIdx.x;
  const int wq = tid & 15, dr = tid >> 4;          // wq: 16 float4 spans of the row; dr: 16 d-rows

  sg[tid]        = g[tid];
  sg[tid + 256]  = g[tid + 256];
  sb2[tid]       = bta[tid];
  sb2[tid + 256] = bta[tid + 256];

  const float* xp = x + ((size_t)(b*512)*128 + h_src)*128 + w0 + wq*4;   // + d*16384

  // ---- pass 1: sums over d (32 float4 loads per thread) ----
  float s0=0.f,s1=0.f,s2=0.f,s3=0.f, q0=0.f,q1=0.f,q2=0.f,q3=0.f;
  #pragma unroll 8
  for (int k = 0; k < 32; ++k){
    float4 v = *(const float4*)(xp + (size_t)(k*16 + dr)*16384);
    s0 += v.x; q0 += v.x*v.x;
    s1 += v.y; q1 += v.y*v.y;
    s2 += v.z; q2 += v.z*v.z;
    s3 += v.w; q3 += v.w*v.w;
  }
  *(float4*)&reds[dr][wq*4] = make_float4(s0,s1,s2,s3);
  *(float4*)&redq[dr][wq*4] = make_float4(q0,q1,q2,q3);
  __syncthreads();

  if (tid < 64){
    float s = 0.f, q = 0.f;
    #pragma unroll
    for (int r = 0; r < 16; ++r){ s += reds[r][tid]; q += redq[r][tid]; }
    float mean = s*(1.f/512.f);
    float rstd = rsqrtf(q*(1.f/512.f) - mean*mean + 1e-5f);
    sstat[tid] = make_float2(mean, rstd);
  }
  __syncthreads();

  const float2 st0 = sstat[wq*4+0];
  const float2 st1 = sstat[wq*4+1];
  const float2 st2 = sstat[wq*4+2];
  const float2 st3 = sstat[wq*4+3];

  const int h_out = (h_src - 4) & 127;
  const int mbase = ((b*16 + (h_out>>3))*16)*64 + (h_out&7)*8;
  const int seg = tid & 15, i0 = tid >> 4;

  // ---- pass 2: 4 chunks of 128 d ----
  for (int c = 0; c < 4; ++c){
    #pragma unroll
    for (int k = 0; k < 8; ++k){
      const int d = c*128 + k*16 + dr;
      float4 v = *(const float4*)(xp + (size_t)d*16384);     // L2-hot re-read
      const float gg = sg[d], bb = sb2[d];
      u16* tr = tile + (size_t)(k*16 + dr)*65 + wq*4;
      tr[0] = f2bf((v.x - st0.x)*st0.y*gg + bb);
      tr[1] = f2bf((v.y - st1.x)*st1.y*gg + bb);
      tr[2] = f2bf((v.z - st2.x)*st2.y*gg + bb);
      tr[3] = f2bf((v.w - st3.x)*st3.y*gg + bb);
    }
    __syncthreads();
    // write-out: 64 rows x 256B chunk; wave = 4 rows x (16 lanes x 16B contiguous)
    #pragma unroll
    for (int p = 0; p < 4; ++p){
      const int i = p*16 + i0;                               // local w (tile column)
      const int w_out = (w0 + i - 4) & 127;
      const int m = mbase + (w_out>>3)*64 + (w_out&7);
      u16x8 o;
      #pragma unroll
      for (int jj = 0; jj < 8; ++jj) o[jj] = tile[(size_t)(seg*8 + jj)*65 + i];
      *(u16x8*)(A + (size_t)m*512 + c*128 + seg*8) = o;
    }
    __syncthreads();
  }
}

// ---------------- K2/K4: NT GEMM  C[M,N] = A[M,K] * B[N,K]^T (+bias), bf16, async LDS staging ----------------
// 128x128 tile, BK=32, 256 thr (2x2 waves, each 64x64 = 4x4 mfma 16x16x32), global_load_lds width=16
template<bool BIAS>
__global__ __launch_bounds__(256) void gemm_nt_k(const u16* __restrict__ A, const u16* __restrict__ B,
                                                 const u16* __restrict__ bias, u16* __restrict__ C,
                                                 int M, int N, int K){
  __shared__ u16 As[128*32];
  __shared__ u16 Bs[128*32];
  const int tid = threadIdx.x, lane = tid & 63, wv = tid >> 6;
  const int q4 = lane >> 4, cc = lane & 15;
  const int m0 = blockIdx.y*128, n0 = blockIdx.x*128;
  const int wm = (wv >> 1)*64, wn = (wv & 1)*64;

  const int lrow = tid >> 2, lgrp = tid & 3;
  const u16* ag0 = A + (size_t)(m0 + lrow)*K + lgrp*8;
  const u16* ag1 = ag0 + (size_t)64*K;
  const u16* bg0 = B + (size_t)(n0 + lrow)*K + lgrp*8;
  const u16* bg1 = bg0 + (size_t)64*K;
  u16* as0 = As + tid*8;  u16* as1 = As + 2048 + tid*8;
  u16* bs0 = Bs + tid*8;  u16* bs1 = Bs + 2048 + tid*8;

  f32x4 acc[4][4] = {};
  for (int k0 = 0; k0 < K; k0 += 32){
    __builtin_amdgcn_global_load_lds(ag0 + k0, as0, 16, 0, 0);
    __builtin_amdgcn_global_load_lds(ag1 + k0, as1, 16, 0, 0);
    __builtin_amdgcn_global_load_lds(bg0 + k0, bs0, 16, 0, 0);
    __builtin_amdgcn_global_load_lds(bg1 + k0, bs1, 16, 0, 0);
    __syncthreads();
    bf16x8 af[4], bfr[4];
    #pragma unroll
    for (int t=0; t<4; ++t){
      u16x8 ta = *(const u16x8*)(As + (wm + t*16 + cc)*32 + q4*8);
      af[t]  = __builtin_bit_cast(bf16x8, ta);
      u16x8 tb = *(const u16x8*)(Bs + (wn + t*16 + cc)*32 + q4*8);
      bfr[t] = __builtin_bit_cast(bf16x8, tb);
    }
    #pragma unroll
    for (int i=0; i<4; ++i)
      #pragma unroll
      for (int j=0; j<4; ++j)
        acc[i][j] = mfma16(af[i], bfr[j], acc[i][j]);
    __syncthreads();
  }
  // epilogue: C/D layout col=lane&15, row=(lane>>4)*4+reg
  #pragma unroll
  for (int j=0; j<4; ++j){
    int col = n0 + wn + j*16 + cc;
    float bv = 0.f;
    if (BIAS) bv = bf2f(bias[col]);
    #pragma unroll
    for (int i=0; i<4; ++i){
      int rbase = m0 + wm + i*16 + q4*4;
      #pragma unroll
      for (int r=0; r<4; ++r)
        C[(size_t)(rbase + r)*N + col] = f2bf(acc[i][j][r] + bv);
    }
  }
}

// ---------------- K3: per-window attention (RoPE + softmax(QK^T)V), bf16 ----------------
// qkv: chunk-local [256 windows * 64 rows, 1536]; O: chunk-local [16384, 512]
__global__ __launch_bounds__(256) void attn_k(const u16* __restrict__ qkv, u16* __restrict__ O){
  __shared__ u16 Psh[4][64*72];   // per-wave P (64x64 bf16, row stride 72)
  const int tid = threadIdx.x, lane = tid & 63, wv = tid >> 6;
  const int q4 = lane >> 4, cc = lane & 15;
  const int w0 = blockIdx.x;
  const size_t base = (size_t)w0*64*1536;
  u16* Pw = Psh[wv];

  float freqj[8];
  #pragma unroll
  for (int j=0; j<8; ++j) freqj[j] = exp2f(-1.6609640474436811f * (float)j);  // 10000^(-j/8)
  const float sgn = (q4 < 2) ? -1.f : 1.f;   // d<16: -partner*sin ; d>=16: +partner*sin
  const bool use_s2 = (q4 & 1) != 0;         // d%16 in [8,16) -> s2-based theta

  for (int hh=0; hh<4; ++hh){
    const int h = wv*4 + hh;
    // --- load Q,K fragments + RoPE (A-layout: m=lane&15, k=q4*8+j) ---
    bf16x8 qf[4], kf[4];
    #pragma unroll
    for (int t=0; t<4; ++t){
      const int l = t*16 + cc;                        // token row within window
      const float sel = use_s2 ? (float)(l & 7) : (float)(l >> 3);
      u16x8 qr = *(const u16x8*)(qkv + base + (size_t)l*1536 + h*32 + q4*8);
      u16x8 kr = *(const u16x8*)(qkv + base + (size_t)l*1536 + 512 + h*32 + q4*8);
      u16x8 qo, ko;
      #pragma unroll
      for (int j=0; j<8; ++j){
        float qv = bf2f(qr[j]), kv = bf2f(kr[j]);
        float qp = __shfl_xor(qv, 32);                // partner lane holds d +/- 16
        float kp = __shfl_xor(kv, 32);
        float sn, cs; __sincosf(sel * freqj[j], &sn, &cs);
        qo[j] = f2bf(qv*cs + sgn*qp*sn);
        ko[j] = f2bf(kv*cs + sgn*kp*sn);
      }
      qf[t] = __builtin_bit_cast(bf16x8, qo);
      kf[t] = __builtin_bit_cast(bf16x8, ko);
    }
    // --- S = Q K^T (16 mfma, K=32 in one step) ---
    f32x4 zero = {0.f, 0.f, 0.f, 0.f};
    f32x4 sacc[4][4];
    #pragma unroll
    for (int i=0; i<4; ++i)
      #pragma unroll
      for (int j=0; j<4; ++j)
        sacc[i][j] = mfma16(qf[i], kf[j], zero);
    // --- softmax over rows; write normalized P (bf16) to LDS ---
    const float scale = 0.17677669529663689f;  // 1/sqrt(32)
    #pragma unroll
    for (int i=0; i<4; ++i){
      #pragma unroll
      for (int r=0; r<4; ++r){
        float v0 = sacc[i][0][r]*scale, v1 = sacc[i][1][r]*scale;
        float v2 = sacc[i][2][r]*scale, v3 = sacc[i][3][r]*scale;
        float mx = fmaxf(fmaxf(v0,v1), fmaxf(v2,v3));
        #pragma unroll
        for (int msk=1; msk<16; msk<<=1) mx = fmaxf(mx, __shfl_xor(mx, msk));
        float e0 = __expf(v0-mx), e1 = __expf(v1-mx), e2 = __expf(v2-mx), e3 = __expf(v3-mx);
        float sm = e0+e1+e2+e3;
        #pragma unroll
        for (int msk=1; msk<16; msk<<=1) sm += __shfl_xor(sm, msk);
        float inv = 1.0f / sm;
        int row = i*16 + q4*4 + r;
        Pw[row*72 +      cc] = f2bf(e0*inv);
        Pw[row*72 + 16 + cc] = f2bf(e1*inv);
        Pw[row*72 + 32 + cc] = f2bf(e2*inv);
        Pw[row*72 + 48 + cc] = f2bf(e3*inv);
      }
    }
    __syncthreads();
    // --- O = P V : P re-read in A-layout from LDS; V B-frags from global ---
    f32x4 oacc[4][2] = {};
    #pragma unroll
    for (int s=0; s<2; ++s){
      bf16x8 vf[2];
      #pragma unroll
      for (int tn=0; tn<2; ++tn){
        u16x8 vv;
        #pragma unroll
        for (int j=0; j<8; ++j){
          int jr = s*32 + q4*8 + j;                  // key index
          vv[j] = qkv[base + (size_t)jr*1536 + 1024 + h*32 + tn*16 + cc];
        }
        vf[tn] = __builtin_bit_cast(bf16x8, vv);
      }
      #pragma unroll
      for (int i=0; i<4; ++i){
        u16x8 pp = *(const u16x8*)(Pw + (i*16 + cc)*72 + s*32 + q4*8);
        bf16x8 pf = __builtin_bit_cast(bf16x8, pp);
        oacc[i][0] = mfma16(pf, vf[0], oacc[i][0]);
        oacc[i][1] = mfma16(pf, vf[1], oacc[i][1]);
      }
    }
    // --- write O (chunk-local rows, cols = head*32+d) ---
    #pragma unroll
    for (int i=0; i<4; ++i)
      #pragma unroll
      for (int tn=0; tn<2; ++tn)
        #pragma unroll
        for (int r=0; r<4; ++r)
          O[(size_t)(w0*64 + i*16 + q4*4 + r)*512 + h*32 + tn*16 + cc] = f2bf(oacc[i][tn][r]);
    __syncthreads();
  }
}

// ---------------- K5: un-window + roll(+4,+4) : C[M,512] bf16 -> out[B,512,128,128] fp32 ----------------
__global__ __launch_bounds__(256) void unpermute_k(const u16* __restrict__ Cm, float* __restrict__ out){
  __shared__ u16 T[64*130];      // [d_loc][w'] with padded stride
  const int tid = threadIdx.x;
  const int hb = blockIdx.x;     // ih*8+s1
  const int b  = blockIdx.y;
  const int ih = hb >> 3, s1 = hb & 7;
  const int h_out = (hb + 4) & 127;
  const int rid = tid >> 1, half = tid & 1;            // read-phase: 128 m-rows x 2 halves
  const int iw = rid >> 3, s2 = rid & 7;
  const size_t m = ((size_t)((b*16 + ih)*16 + iw))*64 + s1*8 + s2;
  const u16* src = Cm + m*512 + half*32;
  const int dl = tid >> 2, wseg = tid & 3;             // write-phase: 64 d-rows x 4 w-segments

  for (int c0=0; c0<512; c0+=64){
    #pragma unroll
    for (int v=0; v<4; ++v){
      u16x8 r = *(const u16x8*)(src + c0 + v*8);
      #pragma unroll
      for (int j=0; j<8; ++j) T[(half*32 + v*8 + j)*130 + rid] = r[j];
    }
    __syncthreads();
    float* dst = out + (((size_t)(b*512 + c0 + dl))*128 + h_out)*128 + wseg*32;
    #pragma unroll
    for (int v=0; v<4; ++v){
      f32x4 o0, o1;
      #pragma unroll
      for (int j=0; j<4; ++j){
        int w = wseg*32 + v*8 + j;
        o0[j] = bf2f(T[dl*130 + ((w - 4) & 127)]);
      }
      #pragma unroll
      for (int j=0; j<4; ++j){
        int w = wseg*32 + v*8 + 4 + j;
        o1[j] = bf2f(T[dl*130 + ((w - 4) & 127)]);
      }
      *(f32x4*)(dst + v*8)     = o0;
      *(f32x4*)(dst + v*8 + 4) = o1;
    }
    __syncthreads();
  }
}

extern "C" void kernel_launch(void* const* d_in, const int* in_sizes, int n_in,
                              void* d_out, int out_size, void* d_ws, size_t ws_size,
                              hipStream_t stream){
  (void)in_sizes; (void)n_in; (void)out_size; (void)ws_size;
  const float* x     = (const float*)d_in[0];
  const float* ln_g  = (const float*)d_in[1];
  const float* ln_b  = (const float*)d_in[2];
  const float* w_qkv = (const float*)d_in[3];
  const float* w_out = (const float*)d_in[4];
  const float* b_out = (const float*)d_in[5];
  char* ws = (char*)d_ws;

  u16* A      = (u16*)ws;                                  // 64 MB: LN out; attn O in-place per chunk
  u16* QKVc   = (u16*)(ws + 67108864);                     // 64 MB: qkv chunk scratch (48MB), then out-proj C
  u16* wqkv_c = (u16*)(ws + 2*67108864);                   // 1.5 MB
  u16* wout_c = (u16*)(ws + 2*67108864 + 1572864);         // 512 KB
  u16* bout_c = (u16*)(ws + 2*67108864 + 1572864 + 524288);

  cvt_params_k<<<4099, 256, 0, stream>>>(w_qkv, w_out, b_out, wqkv_c, wout_c, bout_c);
  ln_fused_k  <<<1024, 256, 0, stream>>>(x, ln_g, ln_b, A);
  // QKV + attention in 4 chunks of 256 windows (16384 rows): qkv chunk 48MB, O in-place over A
  for (int c = 0; c < 4; ++c){
    u16* Ac = A + (size_t)c*16384*512;
    gemm_nt_k<false><<<dim3(12, 128), 256, 0, stream>>>(Ac, wqkv_c, (const u16*)nullptr, QKVc, 16384, 1536, 512);
    attn_k         <<<256, 256, 0, stream>>>(QKVc, Ac);
  }
  gemm_nt_k<true> <<<dim3(4, 512), 256, 0, stream>>>(A, wout_c, bout_c, QKVc, 65536, 512, 512);
  unpermute_k <<<dim3(128, 4), 256, 0, stream>>>(QKVc, (float*)d_out);
}

// Round 10
// 635.418 us; speedup vs baseline: 1.1809x; 1.1229x over previous
//
#include <hip/hip_runtime.h>
#include <hip/hip_bf16.h>

typedef unsigned short u16;
typedef __attribute__((ext_vector_type(8))) __bf16 bf16x8;
typedef __attribute__((ext_vector_type(4))) float f32x4;
typedef __attribute__((ext_vector_type(8))) unsigned short u16x8;

#define DEV __device__ __forceinline__

DEV float bf2f(u16 v){ union{unsigned u; float f;} c; c.u=((unsigned)v)<<16; return c.f; }
DEV u16 f2bf(float f){ union{float f; unsigned u;} c; c.f=f; unsigned r=c.u+0x7FFFu+((c.u>>16)&1u); return (u16)(r>>16); }
DEV f32x4 mfma16(bf16x8 a, bf16x8 b, f32x4 c){ return __builtin_amdgcn_mfma_f32_16x16x32_bf16(a,b,c,0,0,0); }

// dims: B=4, D=512, H=W=128, wsz=8, shift=4, heads=16, dh=32, L=64
// Inputs fp32, output fp32. Core pipeline bf16 MFMA.
// M = 65536 tokens (window-permuted order), window w holds rows [w*64, w*64+64)
// ws: A @0 (64MB, LN out -> attn O in-place) | QKVc @64MB (64MB: qkv chunks / out-proj C)
//     | params @128MB (~2.1MB bf16 copies)

// ---------------- K0: fused param convert fp32 -> bf16 ----------------
__global__ __launch_bounds__(256) void cvt_params_k(const float* __restrict__ wqkv, const float* __restrict__ wout,
                                                    const float* __restrict__ bout,
                                                    u16* __restrict__ wqkv_c, u16* __restrict__ wout_c,
                                                    u16* __restrict__ bout_c){
  int i = blockIdx.x*256 + threadIdx.x;
  if (i < 786432) wqkv_c[i] = f2bf(wqkv[i]);
  int j = i - 786432;
  if (j >= 0 && j < 262144) wout_c[j] = f2bf(wout[j]);
  int k = i - 1048576;
  if (k >= 0 && k < 512) bout_c[k] = f2bf(bout[k]);
}

// ---------------- K1: fused LayerNorm (stats + apply) + roll(-4,-4) + window permute ----------------
// (measured R9: 86 µs, WRITE amplification eliminated; pass-1 256B/hop is DRAM-activate-bound ~2.35 TB/s —
//  contiguity restructure deferred to next round)
__global__ __launch_bounds__(256) void ln_fused_k(const float* __restrict__ x, const float* __restrict__ g,
                                                  const float* __restrict__ bta, u16* __restrict__ A){
  __shared__ float reds[16][64];
  __shared__ float redq[16][64];
  __shared__ float2 sstat[64];
  __shared__ float sg[512], sb2[512];
  __shared__ u16 tile[128*65];

  const int blk = blockIdx.x;
  const int b = blk >> 8, rem = blk & 255;
  const int h_src = rem >> 1, w0 = (rem & 1) << 6;
  const int tid = threadIdx.x;
  const int wq = tid & 15, dr = tid >> 4;          // wq: 16 float4 spans of the row; dr: 16 d-rows

  sg[tid]        = g[tid];
  sg[tid + 256]  = g[tid + 256];
  sb2[tid]       = bta[tid];
  sb2[tid + 256] = bta[tid + 256];

  const float* xp = x + ((size_t)(b*512)*128 + h_src)*128 + w0 + wq*4;   // + d*16384

  // ---- pass 1: sums over d (32 float4 loads per thread) ----
  float s0=0.f,s1=0.f,s2=0.f,s3=0.f, q0=0.f,q1=0.f,q2=0.f,q3=0.f;
  #pragma unroll 8
  for (int k = 0; k < 32; ++k){
    float4 v = *(const float4*)(xp + (size_t)(k*16 + dr)*16384);
    s0 += v.x; q0 += v.x*v.x;
    s1 += v.y; q1 += v.y*v.y;
    s2 += v.z; q2 += v.z*v.z;
    s3 += v.w; q3 += v.w*v.w;
  }
  *(float4*)&reds[dr][wq*4] = make_float4(s0,s1,s2,s3);
  *(float4*)&redq[dr][wq*4] = make_float4(q0,q1,q2,q3);
  __syncthreads();

  if (tid < 64){
    float s = 0.f, q = 0.f;
    #pragma unroll
    for (int r = 0; r < 16; ++r){ s += reds[r][tid]; q += redq[r][tid]; }
    float mean = s*(1.f/512.f);
    float rstd = rsqrtf(q*(1.f/512.f) - mean*mean + 1e-5f);
    sstat[tid] = make_float2(mean, rstd);
  }
  __syncthreads();

  const float2 st0 = sstat[wq*4+0];
  const float2 st1 = sstat[wq*4+1];
  const float2 st2 = sstat[wq*4+2];
  const float2 st3 = sstat[wq*4+3];

  const int h_out = (h_src - 4) & 127;
  const int mbase = ((b*16 + (h_out>>3))*16)*64 + (h_out&7)*8;
  const int seg = tid & 15, i0 = tid >> 4;

  // ---- pass 2: 4 chunks of 128 d ----
  for (int c = 0; c < 4; ++c){
    #pragma unroll
    for (int k = 0; k < 8; ++k){
      const int d = c*128 + k*16 + dr;
      float4 v = *(const float4*)(xp + (size_t)d*16384);     // L3-hot re-read
      const float gg = sg[d], bb = sb2[d];
      u16* tr = tile + (size_t)(k*16 + dr)*65 + wq*4;
      tr[0] = f2bf((v.x - st0.x)*st0.y*gg + bb);
      tr[1] = f2bf((v.y - st1.x)*st1.y*gg + bb);
      tr[2] = f2bf((v.z - st2.x)*st2.y*gg + bb);
      tr[3] = f2bf((v.w - st3.x)*st3.y*gg + bb);
    }
    __syncthreads();
    // write-out: 64 rows x 256B chunk; wave = 4 rows x (16 lanes x 16B contiguous)
    #pragma unroll
    for (int p = 0; p < 4; ++p){
      const int i = p*16 + i0;                               // local w (tile column)
      const int w_out = (w0 + i - 4) & 127;
      const int m = mbase + (w_out>>3)*64 + (w_out&7);
      u16x8 o;
      #pragma unroll
      for (int jj = 0; jj < 8; ++jj) o[jj] = tile[(size_t)(seg*8 + jj)*65 + i];
      *(u16x8*)(A + (size_t)m*512 + c*128 + seg*8) = o;
    }
    __syncthreads();
  }
}

// ---------------- K2/K4: NT GEMM  C[M,N] = A[M,K] * B[N,K]^T (+bias), bf16, async LDS staging ----------------
// 128x128 tile, BK=32, 256 thr (2x2 waves, each 64x64 = 4x4 mfma 16x16x32), global_load_lds width=16
template<bool BIAS>
__global__ __launch_bounds__(256) void gemm_nt_k(const u16* __restrict__ A, const u16* __restrict__ B,
                                                 const u16* __restrict__ bias, u16* __restrict__ C,
                                                 int M, int N, int K){
  __shared__ u16 As[128*32];
  __shared__ u16 Bs[128*32];
  const int tid = threadIdx.x, lane = tid & 63, wv = tid >> 6;
  const int q4 = lane >> 4, cc = lane & 15;
  const int m0 = blockIdx.y*128, n0 = blockIdx.x*128;
  const int wm = (wv >> 1)*64, wn = (wv & 1)*64;

  const int lrow = tid >> 2, lgrp = tid & 3;
  const u16* ag0 = A + (size_t)(m0 + lrow)*K + lgrp*8;
  const u16* ag1 = ag0 + (size_t)64*K;
  const u16* bg0 = B + (size_t)(n0 + lrow)*K + lgrp*8;
  const u16* bg1 = bg0 + (size_t)64*K;
  u16* as0 = As + tid*8;  u16* as1 = As + 2048 + tid*8;
  u16* bs0 = Bs + tid*8;  u16* bs1 = Bs + 2048 + tid*8;

  f32x4 acc[4][4] = {};
  for (int k0 = 0; k0 < K; k0 += 32){
    __builtin_amdgcn_global_load_lds(ag0 + k0, as0, 16, 0, 0);
    __builtin_amdgcn_global_load_lds(ag1 + k0, as1, 16, 0, 0);
    __builtin_amdgcn_global_load_lds(bg0 + k0, bs0, 16, 0, 0);
    __builtin_amdgcn_global_load_lds(bg1 + k0, bs1, 16, 0, 0);
    __syncthreads();
    bf16x8 af[4], bfr[4];
    #pragma unroll
    for (int t=0; t<4; ++t){
      u16x8 ta = *(const u16x8*)(As + (wm + t*16 + cc)*32 + q4*8);
      af[t]  = __builtin_bit_cast(bf16x8, ta);
      u16x8 tb = *(const u16x8*)(Bs + (wn + t*16 + cc)*32 + q4*8);
      bfr[t] = __builtin_bit_cast(bf16x8, tb);
    }
    #pragma unroll
    for (int i=0; i<4; ++i)
      #pragma unroll
      for (int j=0; j<4; ++j)
        acc[i][j] = mfma16(af[i], bfr[j], acc[i][j]);
    __syncthreads();
  }
  // epilogue: C/D layout col=lane&15, row=(lane>>4)*4+reg
  #pragma unroll
  for (int j=0; j<4; ++j){
    int col = n0 + wn + j*16 + cc;
    float bv = 0.f;
    if (BIAS) bv = bf2f(bias[col]);
    #pragma unroll
    for (int i=0; i<4; ++i){
      int rbase = m0 + wm + i*16 + q4*4;
      #pragma unroll
      for (int r=0; r<4; ++r)
        C[(size_t)(rbase + r)*N + col] = f2bf(acc[i][j][r] + bv);
    }
  }
}

// ---------------- K3: per-window attention (RoPE + softmax(QK^T)V), bf16 ----------------
// R10 change: hh loop split across grid (256 -> 1024 blocks): block = (window w0, head-group hh).
// Work per wave identical to R9; O-writes of sibling blocks hit disjoint d-columns.
// 4 blocks/CU (LDS 36.9KB) -> 16 waves/CU to hide scalar V-gather + sincos latency.
__global__ __launch_bounds__(256) void attn_k(const u16* __restrict__ qkv, u16* __restrict__ O){
  __shared__ u16 Psh[4][64*72];   // per-wave P (64x64 bf16, row stride 72)
  const int tid = threadIdx.x, lane = tid & 63, wv = tid >> 6;
  const int q4 = lane >> 4, cc = lane & 15;
  const int w0 = blockIdx.x >> 2;
  const int hh = blockIdx.x & 3;
  const size_t base = (size_t)w0*64*1536;
  u16* Pw = Psh[wv];

  float freqj[8];
  #pragma unroll
  for (int j=0; j<8; ++j) freqj[j] = exp2f(-1.6609640474436811f * (float)j);  // 10000^(-j/8)
  const float sgn = (q4 < 2) ? -1.f : 1.f;   // d<16: -partner*sin ; d>=16: +partner*sin
  const bool use_s2 = (q4 & 1) != 0;         // d%16 in [8,16) -> s2-based theta

  const int h = wv*4 + hh;
  // --- load Q,K fragments + RoPE (A-layout: m=lane&15, k=q4*8+j) ---
  bf16x8 qf[4], kf[4];
  #pragma unroll
  for (int t=0; t<4; ++t){
    const int l = t*16 + cc;                        // token row within window
    const float sel = use_s2 ? (float)(l & 7) : (float)(l >> 3);
    u16x8 qr = *(const u16x8*)(qkv + base + (size_t)l*1536 + h*32 + q4*8);
    u16x8 kr = *(const u16x8*)(qkv + base + (size_t)l*1536 + 512 + h*32 + q4*8);
    u16x8 qo, ko;
    #pragma unroll
    for (int j=0; j<8; ++j){
      float qv = bf2f(qr[j]), kv = bf2f(kr[j]);
      float qp = __shfl_xor(qv, 32);                // partner lane holds d +/- 16
      float kp = __shfl_xor(kv, 32);
      float sn, cs; __sincosf(sel * freqj[j], &sn, &cs);
      qo[j] = f2bf(qv*cs + sgn*qp*sn);
      ko[j] = f2bf(kv*cs + sgn*kp*sn);
    }
    qf[t] = __builtin_bit_cast(bf16x8, qo);
    kf[t] = __builtin_bit_cast(bf16x8, ko);
  }
  // --- S = Q K^T (16 mfma, K=32 in one step) ---
  f32x4 zero = {0.f, 0.f, 0.f, 0.f};
  f32x4 sacc[4][4];
  #pragma unroll
  for (int i=0; i<4; ++i)
    #pragma unroll
    for (int j=0; j<4; ++j)
      sacc[i][j] = mfma16(qf[i], kf[j], zero);
  // --- softmax over rows; write normalized P (bf16) to LDS ---
  const float scale = 0.17677669529663689f;  // 1/sqrt(32)
  #pragma unroll
  for (int i=0; i<4; ++i){
    #pragma unroll
    for (int r=0; r<4; ++r){
      float v0 = sacc[i][0][r]*scale, v1 = sacc[i][1][r]*scale;
      float v2 = sacc[i][2][r]*scale, v3 = sacc[i][3][r]*scale;
      float mx = fmaxf(fmaxf(v0,v1), fmaxf(v2,v3));
      #pragma unroll
      for (int msk=1; msk<16; msk<<=1) mx = fmaxf(mx, __shfl_xor(mx, msk));
      float e0 = __expf(v0-mx), e1 = __expf(v1-mx), e2 = __expf(v2-mx), e3 = __expf(v3-mx);
      float sm = e0+e1+e2+e3;
      #pragma unroll
      for (int msk=1; msk<16; msk<<=1) sm += __shfl_xor(sm, msk);
      float inv = 1.0f / sm;
      int row = i*16 + q4*4 + r;
      Pw[row*72 +      cc] = f2bf(e0*inv);
      Pw[row*72 + 16 + cc] = f2bf(e1*inv);
      Pw[row*72 + 32 + cc] = f2bf(e2*inv);
      Pw[row*72 + 48 + cc] = f2bf(e3*inv);
    }
  }
  __syncthreads();
  // --- O = P V : P re-read in A-layout from LDS; V B-frags from global ---
  f32x4 oacc[4][2] = {};
  #pragma unroll
  for (int s=0; s<2; ++s){
    bf16x8 vf[2];
    #pragma unroll
    for (int tn=0; tn<2; ++tn){
      u16x8 vv;
      #pragma unroll
      for (int j=0; j<8; ++j){
        int jr = s*32 + q4*8 + j;                  // key index
        vv[j] = qkv[base + (size_t)jr*1536 + 1024 + h*32 + tn*16 + cc];
      }
      vf[tn] = __builtin_bit_cast(bf16x8, vv);
    }
    #pragma unroll
    for (int i=0; i<4; ++i){
      u16x8 pp = *(const u16x8*)(Pw + (i*16 + cc)*72 + s*32 + q4*8);
      bf16x8 pf = __builtin_bit_cast(bf16x8, pp);
      oacc[i][0] = mfma16(pf, vf[0], oacc[i][0]);
      oacc[i][1] = mfma16(pf, vf[1], oacc[i][1]);
    }
  }
  // --- write O (chunk-local rows, cols = head*32+d) ---
  #pragma unroll
  for (int i=0; i<4; ++i)
    #pragma unroll
    for (int tn=0; tn<2; ++tn)
      #pragma unroll
      for (int r=0; r<4; ++r)
        O[(size_t)(w0*64 + i*16 + q4*4 + r)*512 + h*32 + tn*16 + cc] = f2bf(oacc[i][tn][r]);
}

// ---------------- K5: un-window + roll(+4,+4) : C[M,512] bf16 -> out[B,512,128,128] fp32 ----------------
__global__ __launch_bounds__(256) void unpermute_k(const u16* __restrict__ Cm, float* __restrict__ out){
  __shared__ u16 T[64*130];      // [d_loc][w'] with padded stride
  const int tid = threadIdx.x;
  const int hb = blockIdx.x;     // ih*8+s1
  const int b  = blockIdx.y;
  const int ih = hb >> 3, s1 = hb & 7;
  const int h_out = (hb + 4) & 127;
  const int rid = tid >> 1, half = tid & 1;            // read-phase: 128 m-rows x 2 halves
  const int iw = rid >> 3, s2 = rid & 7;
  const size_t m = ((size_t)((b*16 + ih)*16 + iw))*64 + s1*8 + s2;
  const u16* src = Cm + m*512 + half*32;
  const int dl = tid >> 2, wseg = tid & 3;             // write-phase: 64 d-rows x 4 w-segments

  for (int c0=0; c0<512; c0+=64){
    #pragma unroll
    for (int v=0; v<4; ++v){
      u16x8 r = *(const u16x8*)(src + c0 + v*8);
      #pragma unroll
      for (int j=0; j<8; ++j) T[(half*32 + v*8 + j)*130 + rid] = r[j];
    }
    __syncthreads();
    float* dst = out + (((size_t)(b*512 + c0 + dl))*128 + h_out)*128 + wseg*32;
    #pragma unroll
    for (int v=0; v<4; ++v){
      f32x4 o0, o1;
      #pragma unroll
      for (int j=0; j<4; ++j){
        int w = wseg*32 + v*8 + j;
        o0[j] = bf2f(T[dl*130 + ((w - 4) & 127)]);
      }
      #pragma unroll
      for (int j=0; j<4; ++j){
        int w = wseg*32 + v*8 + 4 + j;
        o1[j] = bf2f(T[dl*130 + ((w - 4) & 127)]);
      }
      *(f32x4*)(dst + v*8)     = o0;
      *(f32x4*)(dst + v*8 + 4) = o1;
    }
    __syncthreads();
  }
}

extern "C" void kernel_launch(void* const* d_in, const int* in_sizes, int n_in,
                              void* d_out, int out_size, void* d_ws, size_t ws_size,
                              hipStream_t stream){
  (void)in_sizes; (void)n_in; (void)out_size; (void)ws_size;
  const float* x     = (const float*)d_in[0];
  const float* ln_g  = (const float*)d_in[1];
  const float* ln_b  = (const float*)d_in[2];
  const float* w_qkv = (const float*)d_in[3];
  const float* w_out = (const float*)d_in[4];
  const float* b_out = (const float*)d_in[5];
  char* ws = (char*)d_ws;

  u16* A      = (u16*)ws;                                  // 64 MB: LN out; attn O in-place per chunk
  u16* QKVc   = (u16*)(ws + 67108864);                     // 64 MB: qkv chunk scratch (48MB), then out-proj C
  u16* wqkv_c = (u16*)(ws + 2*67108864);                   // 1.5 MB
  u16* wout_c = (u16*)(ws + 2*67108864 + 1572864);         // 512 KB
  u16* bout_c = (u16*)(ws + 2*67108864 + 1572864 + 524288);

  cvt_params_k<<<4099, 256, 0, stream>>>(w_qkv, w_out, b_out, wqkv_c, wout_c, bout_c);
  ln_fused_k  <<<1024, 256, 0, stream>>>(x, ln_g, ln_b, A);
  // QKV + attention in 4 chunks of 256 windows (16384 rows): qkv chunk 48MB, O in-place over A
  for (int c = 0; c < 4; ++c){
    u16* Ac = A + (size_t)c*16384*512;
    gemm_nt_k<false><<<dim3(12, 128), 256, 0, stream>>>(Ac, wqkv_c, (const u16*)nullptr, QKVc, 16384, 1536, 512);
    attn_k         <<<1024, 256, 0, stream>>>(QKVc, Ac);
  }
  gemm_nt_k<true> <<<dim3(4, 512), 256, 0, stream>>>(A, wout_c, bout_c, QKVc, 65536, 512, 512);
  unpermute_k <<<dim3(128, 4), 256, 0, stream>>>(QKVc, (float*)d_out);
}

// Round 13
// 634.580 us; speedup vs baseline: 1.1825x; 1.0013x over previous
//
#include <hip/hip_runtime.h>
#include <hip/hip_bf16.h>

typedef unsigned short u16;
typedef __attribute__((ext_vector_type(8))) __bf16 bf16x8;
typedef __attribute__((ext_vector_type(4))) float f32x4;
typedef __attribute__((ext_vector_type(8))) unsigned short u16x8;

#define DEV __device__ __forceinline__

DEV float bf2f(u16 v){ union{unsigned u; float f;} c; c.u=((unsigned)v)<<16; return c.f; }
DEV u16 f2bf(float f){ union{float f; unsigned u;} c; c.f=f; unsigned r=c.u+0x7FFFu+((c.u>>16)&1u); return (u16)(r>>16); }
DEV f32x4 mfma16(bf16x8 a, bf16x8 b, f32x4 c){ return __builtin_amdgcn_mfma_f32_16x16x32_bf16(a,b,c,0,0,0); }

// dims: B=4, D=512, H=W=128, wsz=8, shift=4, heads=16, dh=32, L=64
// ws: A @0 (64MB) | QKVc @64MB (64MB) | params @128MB

// ---------------- K0: fused param convert fp32 -> bf16 ----------------
__global__ __launch_bounds__(256) void cvt_params_k(const float* __restrict__ wqkv, const float* __restrict__ wout,
                                                    const float* __restrict__ bout,
                                                    u16* __restrict__ wqkv_c, u16* __restrict__ wout_c,
                                                    u16* __restrict__ bout_c){
  int i = blockIdx.x*256 + threadIdx.x;
  if (i < 786432) wqkv_c[i] = f2bf(wqkv[i]);
  int j = i - 786432;
  if (j >= 0 && j < 262144) wout_c[j] = f2bf(wout[j]);
  int k = i - 1048576;
  if (k >= 0 && k < 512) bout_c[k] = f2bf(bout[k]);
}

// ---------------- K1: fused LayerNorm + roll(-4,-4) + window permute ----------------
// R11: block = (b, h_src) covering the FULL 128-w row -> 512B contiguous per d-hop
// (R9/R10 measured 2.35 TB/s pinned at 256B/hop; burst-size is the theory under test).
// 512 blocks x 512 threads. reds/redq overlaid on tile (LDS ~38KB). Stores unchanged:
// wave-contiguous 256B full-line segments.
__global__ __launch_bounds__(512) void ln_fused_k(const float* __restrict__ x, const float* __restrict__ g,
                                                  const float* __restrict__ bta, u16* __restrict__ A){
  __shared__ __align__(16) u16 tile[128*130];   // pass2 tile [128 d][130]; pass1 overlays reds/redq (16KB)
  __shared__ float2 sstat[128];
  __shared__ float sg[512], sb2[512];
  float* reds = (float*)tile;                   // [16][128]
  float* redq = reds + 16*128;                  // [16][128]

  const int blk = blockIdx.x;
  const int b = blk >> 7, h_src = blk & 127;
  const int tid = threadIdx.x;
  const int wq = tid & 31, dr = tid >> 5;       // wq: 32 float4 spans of the 128-w row; dr: 16 d-rows

  sg[tid]  = g[tid];
  sb2[tid] = bta[tid];

  const float* xp = x + ((size_t)(b*512)*128 + h_src)*128 + wq*4;   // + d*16384

  // ---- pass 1: sums over d (32 float4 loads per thread) ----
  float s0=0.f,s1=0.f,s2=0.f,s3=0.f, q0=0.f,q1=0.f,q2=0.f,q3=0.f;
  #pragma unroll 8
  for (int k = 0; k < 32; ++k){
    float4 v = *(const float4*)(xp + (size_t)(k*16 + dr)*16384);
    s0 += v.x; q0 += v.x*v.x;
    s1 += v.y; q1 += v.y*v.y;
    s2 += v.z; q2 += v.z*v.z;
    s3 += v.w; q3 += v.w*v.w;
  }
  *(float4*)&reds[dr*128 + wq*4] = make_float4(s0,s1,s2,s3);
  *(float4*)&redq[dr*128 + wq*4] = make_float4(q0,q1,q2,q3);
  __syncthreads();

  if (tid < 128){
    float s = 0.f, q = 0.f;
    #pragma unroll
    for (int r = 0; r < 16; ++r){ s += reds[r*128 + tid]; q += redq[r*128 + tid]; }
    float mean = s*(1.f/512.f);
    float rstd = rsqrtf(q*(1.f/512.f) - mean*mean + 1e-5f);
    sstat[tid] = make_float2(mean, rstd);
  }
  __syncthreads();                              // after this, reds/redq dead -> tile reuse safe

  const float2 st0 = sstat[wq*4+0];
  const float2 st1 = sstat[wq*4+1];
  const float2 st2 = sstat[wq*4+2];
  const float2 st3 = sstat[wq*4+3];

  const int h_out = (h_src - 4) & 127;
  const int mbase = ((b*16 + (h_out>>3))*16)*64 + (h_out&7)*8;
  const int seg = tid & 15, i0 = tid >> 4;      // write phase: 16 d-segs x 32 positions

  // ---- pass 2: 4 chunks of 128 d ----
  for (int c = 0; c < 4; ++c){
    __syncthreads();                            // tile from previous chunk fully consumed
    #pragma unroll
    for (int k = 0; k < 8; ++k){
      const int d = c*128 + k*16 + dr;
      float4 v = *(const float4*)(xp + (size_t)d*16384);     // cache-hot re-read
      const float gg = sg[d], bb = sb2[d];
      u16* tr = tile + (size_t)(k*16 + dr)*130 + wq*4;
      tr[0] = f2bf((v.x - st0.x)*st0.y*gg + bb);
      tr[1] = f2bf((v.y - st1.x)*st1.y*gg + bb);
      tr[2] = f2bf((v.z - st2.x)*st2.y*gg + bb);
      tr[3] = f2bf((v.w - st3.x)*st3.y*gg + bb);
    }
    __syncthreads();
    // write-out: 128 positions x 256B segment; wave = 4 positions x (16 lanes x 16B contiguous)
    #pragma unroll
    for (int p = 0; p < 4; ++p){
      const int i = p*32 + i0;                               // local w (tile column)
      const int w_out = (i - 4) & 127;
      const int m = mbase + (w_out>>3)*64 + (w_out&7);
      u16x8 o;
      #pragma unroll
      for (int jj = 0; jj < 8; ++jj) o[jj] = tile[(size_t)(seg*8 + jj)*130 + i];
      *(u16x8*)(A + (size_t)m*512 + c*128 + seg*8) = o;
    }
  }
}

// ---------------- K2/K4: NT GEMM  C[M,N] = A[M,K] * B[N,K]^T (+bias), bf16, async LDS staging ----------------
template<bool BIAS>
__global__ __launch_bounds__(256) void gemm_nt_k(const u16* __restrict__ A, const u16* __restrict__ B,
                                                 const u16* __restrict__ bias, u16* __restrict__ C,
                                                 int M, int N, int K){
  __shared__ u16 As[128*32];
  __shared__ u16 Bs[128*32];
  const int tid = threadIdx.x, lane = tid & 63, wv = tid >> 6;
  const int q4 = lane >> 4, cc = lane & 15;
  const int m0 = blockIdx.y*128, n0 = blockIdx.x*128;
  const int wm = (wv >> 1)*64, wn = (wv & 1)*64;

  const int lrow = tid >> 2, lgrp = tid & 3;
  const u16* ag0 = A + (size_t)(m0 + lrow)*K + lgrp*8;
  const u16* ag1 = ag0 + (size_t)64*K;
  const u16* bg0 = B + (size_t)(n0 + lrow)*K + lgrp*8;
  const u16* bg1 = bg0 + (size_t)64*K;
  u16* as0 = As + tid*8;  u16* as1 = As + 2048 + tid*8;
  u16* bs0 = Bs + tid*8;  u16* bs1 = Bs + 2048 + tid*8;

  f32x4 acc[4][4] = {};
  for (int k0 = 0; k0 < K; k0 += 32){
    __builtin_amdgcn_global_load_lds(ag0 + k0, as0, 16, 0, 0);
    __builtin_amdgcn_global_load_lds(ag1 + k0, as1, 16, 0, 0);
    __builtin_amdgcn_global_load_lds(bg0 + k0, bs0, 16, 0, 0);
    __builtin_amdgcn_global_load_lds(bg1 + k0, bs1, 16, 0, 0);
    __syncthreads();
    bf16x8 af[4], bfr[4];
    #pragma unroll
    for (int t=0; t<4; ++t){
      u16x8 ta = *(const u16x8*)(As + (wm + t*16 + cc)*32 + q4*8);
      af[t]  = __builtin_bit_cast(bf16x8, ta);
      u16x8 tb = *(const u16x8*)(Bs + (wn + t*16 + cc)*32 + q4*8);
      bfr[t] = __builtin_bit_cast(bf16x8, tb);
    }
    #pragma unroll
    for (int i=0; i<4; ++i)
      #pragma unroll
      for (int j=0; j<4; ++j)
        acc[i][j] = mfma16(af[i], bfr[j], acc[i][j]);
    __syncthreads();
  }
  // epilogue: C/D layout col=lane&15, row=(lane>>4)*4+reg
  #pragma unroll
  for (int j=0; j<4; ++j){
    int col = n0 + wn + j*16 + cc;
    float bv = 0.f;
    if (BIAS) bv = bf2f(bias[col]);
    #pragma unroll
    for (int i=0; i<4; ++i){
      int rbase = m0 + wm + i*16 + q4*4;
      #pragma unroll
      for (int r=0; r<4; ++r)
        C[(size_t)(rbase + r)*N + col] = f2bf(acc[i][j][r] + bv);
    }
  }
}

// ---------------- K3: per-window attention (RoPE + softmax(QK^T)V), bf16 ----------------
// block = (window w0, head-group hh); 4 blocks/CU, 16 waves/CU.
// R11: __syncthreads() removed — P buffer is wave-private (Psh[wv]); same-wave
// ds_write->ds_read ordering is enforced by compiler lgkmcnt.
__global__ __launch_bounds__(256) void attn_k(const u16* __restrict__ qkv, u16* __restrict__ O){
  __shared__ u16 Psh[4][64*72];   // per-wave P (64x64 bf16, row stride 72)
  const int tid = threadIdx.x, lane = tid & 63, wv = tid >> 6;
  const int q4 = lane >> 4, cc = lane & 15;
  const int w0 = blockIdx.x >> 2;
  const int hh = blockIdx.x & 3;
  const size_t base = (size_t)w0*64*1536;
  u16* Pw = Psh[wv];

  float freqj[8];
  #pragma unroll
  for (int j=0; j<8; ++j) freqj[j] = exp2f(-1.6609640474436811f * (float)j);  // 10000^(-j/8)
  const float sgn = (q4 < 2) ? -1.f : 1.f;
  const bool use_s2 = (q4 & 1) != 0;

  const int h = wv*4 + hh;
  // --- load Q,K fragments + RoPE (A-layout: m=lane&15, k=q4*8+j) ---
  bf16x8 qf[4], kf[4];
  #pragma unroll
  for (int t=0; t<4; ++t){
    const int l = t*16 + cc;
    const float sel = use_s2 ? (float)(l & 7) : (float)(l >> 3);
    u16x8 qr = *(const u16x8*)(qkv + base + (size_t)l*1536 + h*32 + q4*8);
    u16x8 kr = *(const u16x8*)(qkv + base + (size_t)l*1536 + 512 + h*32 + q4*8);
    u16x8 qo, ko;
    #pragma unroll
    for (int j=0; j<8; ++j){
      float qv = bf2f(qr[j]), kv = bf2f(kr[j]);
      float qp = __shfl_xor(qv, 32);
      float kp = __shfl_xor(kv, 32);
      float sn, cs; __sincosf(sel * freqj[j], &sn, &cs);
      qo[j] = f2bf(qv*cs + sgn*qp*sn);
      ko[j] = f2bf(kv*cs + sgn*kp*sn);
    }
    qf[t] = __builtin_bit_cast(bf16x8, qo);
    kf[t] = __builtin_bit_cast(bf16x8, ko);
  }
  // --- S = Q K^T ---
  f32x4 zero = {0.f, 0.f, 0.f, 0.f};
  f32x4 sacc[4][4];
  #pragma unroll
  for (int i=0; i<4; ++i)
    #pragma unroll
    for (int j=0; j<4; ++j)
      sacc[i][j] = mfma16(qf[i], kf[j], zero);
  // --- softmax over rows; write normalized P (bf16) to wave-private LDS ---
  const float scale = 0.17677669529663689f;  // 1/sqrt(32)
  #pragma unroll
  for (int i=0; i<4; ++i){
    #pragma unroll
    for (int r=0; r<4; ++r){
      float v0 = sacc[i][0][r]*scale, v1 = sacc[i][1][r]*scale;
      float v2 = sacc[i][2][r]*scale, v3 = sacc[i][3][r]*scale;
      float mx = fmaxf(fmaxf(v0,v1), fmaxf(v2,v3));
      #pragma unroll
      for (int msk=1; msk<16; msk<<=1) mx = fmaxf(mx, __shfl_xor(mx, msk));
      float e0 = __expf(v0-mx), e1 = __expf(v1-mx), e2 = __expf(v2-mx), e3 = __expf(v3-mx);
      float sm = e0+e1+e2+e3;
      #pragma unroll
      for (int msk=1; msk<16; msk<<=1) sm += __shfl_xor(sm, msk);
      float inv = 1.0f / sm;
      int row = i*16 + q4*4 + r;
      Pw[row*72 +      cc] = f2bf(e0*inv);
      Pw[row*72 + 16 + cc] = f2bf(e1*inv);
      Pw[row*72 + 32 + cc] = f2bf(e2*inv);
      Pw[row*72 + 48 + cc] = f2bf(e3*inv);
    }
  }
  // (no barrier: P is wave-private)
  // --- O = P V ---
  f32x4 oacc[4][2] = {};
  #pragma unroll
  for (int s=0; s<2; ++s){
    bf16x8 vf[2];
    #pragma unroll
    for (int tn=0; tn<2; ++tn){
      u16x8 vv;
      #pragma unroll
      for (int j=0; j<8; ++j){
        int jr = s*32 + q4*8 + j;
        vv[j] = qkv[base + (size_t)jr*1536 + 1024 + h*32 + tn*16 + cc];
      }
      vf[tn] = __builtin_bit_cast(bf16x8, vv);
    }
    #pragma unroll
    for (int i=0; i<4; ++i){
      u16x8 pp = *(const u16x8*)(Pw + (i*16 + cc)*72 + s*32 + q4*8);
      bf16x8 pf = __builtin_bit_cast(bf16x8, pp);
      oacc[i][0] = mfma16(pf, vf[0], oacc[i][0]);
      oacc[i][1] = mfma16(pf, vf[1], oacc[i][1]);
    }
  }
  // --- write O ---
  #pragma unroll
  for (int i=0; i<4; ++i)
    #pragma unroll
    for (int tn=0; tn<2; ++tn)
      #pragma unroll
      for (int r=0; r<4; ++r)
        O[(size_t)(w0*64 + i*16 + q4*4 + r)*512 + h*32 + tn*16 + cc] = f2bf(oacc[i][tn][r]);
}

// ---------------- K5: un-window + roll(+4,+4) : C[M,512] bf16 -> out[B,512,128,128] fp32 ----------------
__global__ __launch_bounds__(256) void unpermute_k(const u16* __restrict__ Cm, float* __restrict__ out){
  __shared__ u16 T[64*130];      // [d_loc][w'] with padded stride
  const int tid = threadIdx.x;
  const int hb = blockIdx.x;     // ih*8+s1
  const int b  = blockIdx.y;
  const int ih = hb >> 3, s1 = hb & 7;
  const int h_out = (hb + 4) & 127;
  const int rid = tid >> 1, half = tid & 1;            // read-phase: 128 m-rows x 2 halves
  const int iw = rid >> 3, s2 = rid & 7;
  const size_t m = ((size_t)((b*16 + ih)*16 + iw))*64 + s1*8 + s2;
  const u16* src = Cm + m*512 + half*32;
  const int dl = tid >> 2, wseg = tid & 3;             // write-phase: 64 d-rows x 4 w-segments

  for (int c0=0; c0<512; c0+=64){
    #pragma unroll
    for (int v=0; v<4; ++v){
      u16x8 r = *(const u16x8*)(src + c0 + v*8);
      #pragma unroll
      for (int j=0; j<8; ++j) T[(half*32 + v*8 + j)*130 + rid] = r[j];
    }
    __syncthreads();
    float* dst = out + (((size_t)(b*512 + c0 + dl))*128 + h_out)*128 + wseg*32;
    #pragma unroll
    for (int v=0; v<4; ++v){
      f32x4 o0, o1;
      #pragma unroll
      for (int j=0; j<4; ++j){
        int w = wseg*32 + v*8 + j;
        o0[j] = bf2f(T[dl*130 + ((w - 4) & 127)]);
      }
      #pragma unroll
      for (int j=0; j<4; ++j){
        int w = wseg*32 + v*8 + 4 + j;
        o1[j] = bf2f(T[dl*130 + ((w - 4) & 127)]);
      }
      *(f32x4*)(dst + v*8)     = o0;
      *(f32x4*)(dst + v*8 + 4) = o1;
    }
    __syncthreads();
  }
}

extern "C" void kernel_launch(void* const* d_in, const int* in_sizes, int n_in,
                              void* d_out, int out_size, void* d_ws, size_t ws_size,
                              hipStream_t stream){
  (void)in_sizes; (void)n_in; (void)out_size; (void)ws_size;
  const float* x     = (const float*)d_in[0];
  const float* ln_g  = (const float*)d_in[1];
  const float* ln_b  = (const float*)d_in[2];
  const float* w_qkv = (const float*)d_in[3];
  const float* w_out = (const float*)d_in[4];
  const float* b_out = (const float*)d_in[5];
  char* ws = (char*)d_ws;

  u16* A      = (u16*)ws;                                  // 64 MB: LN out; attn O in-place per chunk
  u16* QKVc   = (u16*)(ws + 67108864);                     // 64 MB: qkv chunk scratch (48MB), then out-proj C
  u16* wqkv_c = (u16*)(ws + 2*67108864);                   // 1.5 MB
  u16* wout_c = (u16*)(ws + 2*67108864 + 1572864);         // 512 KB
  u16* bout_c = (u16*)(ws + 2*67108864 + 1572864 + 524288);

  cvt_params_k<<<4099, 256, 0, stream>>>(w_qkv, w_out, b_out, wqkv_c, wout_c, bout_c);
  ln_fused_k  <<<512, 512, 0, stream>>>(x, ln_g, ln_b, A);
  // QKV + attention in 4 chunks of 256 windows (16384 rows)
  for (int c = 0; c < 4; ++c){
    u16* Ac = A + (size_t)c*16384*512;
    gemm_nt_k<false><<<dim3(12, 128), 256, 0, stream>>>(Ac, wqkv_c, (const u16*)nullptr, QKVc, 16384, 1536, 512);
    attn_k         <<<1024, 256, 0, stream>>>(QKVc, Ac);
  }
  gemm_nt_k<true> <<<dim3(4, 512), 256, 0, stream>>>(A, wout_c, bout_c, QKVc, 65536, 512, 512);
  unpermute_k <<<dim3(128, 4), 256, 0, stream>>>(QKVc, (float*)d_out);
}